// Round 8
// baseline (1119.884 us; speedup 1.0000x reference)
//
#include <hip/hip_runtime.h>
#include <hip/hip_bf16.h>
#include <stdint.h>

#define Rdim 1023
#define BFR  4190208           // 64*64*1023

typedef __bf16 bf16;
typedef __bf16 bf16x8 __attribute__((ext_vector_type(8)));
typedef __bf16 bf16x4 __attribute__((ext_vector_type(4)));
typedef float  f32x4  __attribute__((ext_vector_type(4)));
typedef float  f32x4u __attribute__((ext_vector_type(4), aligned(4)));

__device__ __forceinline__ void async16(const void* g, void* l) {
    __builtin_amdgcn_global_load_lds(
        (const __attribute__((address_space(1))) void*)g,
        (__attribute__((address_space(3))) void*)l, 16, 0, 0);
}

// ---------------------------------------------------------------------------
// Producer helpers (bodies identical to r7's proven k_prep, re-parameterized)
// Swizzle: 16B chunk c of row m stored at chunk (c ^ (m&7)) within its 128B
// window -> GEMM staging stays a LINEAR copy, ds_read applies the same XOR.
// ---------------------------------------------------------------------------
__device__ __forceinline__ void prep_args_row(
    int m, int t, const float* __restrict__ x,
    const float* __restrict__ w0, const float* __restrict__ w1,
    const float* __restrict__ w2, const float* __restrict__ w3,
    bf16* __restrict__ args)
{
    const int b = m >> 6;
    float wr0[16], wr1[16], wr2[16], wr3[16];
#pragma unroll
    for (int l = 0; l < 16; ++l) {
        wr0[l] = w0[b*16 + l]; wr1[l] = w1[b*16 + l];
        wr2[l] = w2[b*16 + l]; wr3[l] = w3[b*16 + l];
    }
    const float* xb = x + ((size_t)(b*16)*64 + (m & 63)) * (size_t)Rdim;
    float a0[4] = {}, a1[4] = {}, a2[4] = {}, a3[4] = {};
    if (t < 255) {
#pragma unroll
        for (int l = 0; l < 16; ++l) {
            f32x4u v = *(const f32x4u*)(xb + (size_t)l*(64*(size_t)Rdim) + t*4);
#pragma unroll
            for (int j = 0; j < 4; ++j) {
                a0[j] += wr0[l]*v[j]; a1[j] += wr1[l]*v[j];
                a2[j] += wr2[l]*v[j]; a3[j] += wr3[l]*v[j];
            }
        }
    } else {
#pragma unroll
        for (int l = 0; l < 16; ++l) {
            const float* p = xb + (size_t)l*(64*(size_t)Rdim) + 1020;
#pragma unroll
            for (int j = 0; j < 3; ++j) {
                float v = p[j];
                a0[j] += wr0[l]*v; a1[j] += wr1[l]*v;
                a2[j] += wr2[l]*v; a3[j] += wr3[l]*v;
            }
        }
    }
    const int c   = t >> 1;
    const int S   = m & 7;
    const int off = ((c ^ S) << 3) + ((t & 1) << 2);
    bf16x4 s0, s1, s2, s3;
#pragma unroll
    for (int j = 0; j < 4; ++j) {
        s0[j] = (bf16)a0[j]; s1[j] = (bf16)a1[j];
        s2[j] = (bf16)a2[j]; s3[j] = (bf16)a3[j];
    }
    *(bf16x4*)(args +            (size_t)m*1024 + off) = s0;   // car
    *(bf16x4*)(args + 4194304 +  (size_t)m*1024 + off) = s1;   // cdr
    bf16* c12 = args + 8388608 + (size_t)m*2048;
    *(bf16x4*)(c12 + off)        = s2;                         // c1
    *(bf16x4*)(c12 + 1024 + off) = s3;                         // c2
}

__device__ __forceinline__ void prep_dpad_chunk(
    int id, const float* __restrict__ Dl, const float* __restrict__ Dr,
    const float* __restrict__ El, const float* __restrict__ Er,
    bf16* __restrict__ dpad)
{
    const float* src; int n, c, K; size_t base;
    if (id < 262144) {
        const int m2  = id >> 17;
        src = m2 ? Dr : Dl;
        const int rem = id & 131071;
        n = rem >> 7; c = rem & 127; K = 1024;
        base = m2 ? 1048576u : 0u;
    } else {
        const int rem = id - 262144;
        n = rem >> 8; c = rem & 255; K = 2048;
        base = 2097152u;
        src = (c < 128) ? El : Er;
    }
    const int cl = c & 127;
    float v[8] = {};
    if (n < Rdim) {
        const float* sp = src + (size_t)n*Rdim + cl*8;
        if (cl < 127) {
            f32x4u u0 = *(const f32x4u*)sp;
            f32x4u u1 = *(const f32x4u*)(sp + 4);
#pragma unroll
            for (int j = 0; j < 4; ++j) { v[j] = u0[j]; v[4+j] = u1[j]; }
        } else {
            f32x4u u0 = *(const f32x4u*)sp;
#pragma unroll
            for (int j = 0; j < 4; ++j) v[j] = u0[j];
            v[4] = sp[4]; v[5] = sp[5]; v[6] = sp[6];
        }
    }
    const int swc = c ^ (n & 7);
    bf16x8 s;
#pragma unroll
    for (int j = 0; j < 8; ++j) s[j] = (bf16)v[j];
    *(bf16x8*)(dpad + base + (size_t)n*K + swc*8) = s;
}

__device__ __forceinline__ void prep_stats(
    int t, const float* __restrict__ w0, const float* __restrict__ w1,
    const float* __restrict__ w2, const float* __restrict__ w3,
    float* __restrict__ out)
{
    const int k = t >> 6, b2 = t & 63;
    const float* w = (k==0) ? w0 : (k==1) ? w1 : (k==2) ? w2 : w3;
    float s = 0.f, mx = -1e30f;
#pragma unroll
    for (int l = 0; l < 16; ++l) {
        float p = w[b2*16 + l];
        s += p * logf(p + 1e-12f);
        mx = fmaxf(mx, p);
    }
    out[3*(size_t)BFR +       k*64 + b2] = -s / logf(16.f);
    out[3*(size_t)BFR + 256 + k*64 + b2] = mx;
}

// ---------------------------------------------------------------------------
// GEMM tile (r7's proven 1-phase pipeline, verbatim, parameterized).
// 128x256 tile, 16x16x32 MFMA, 8 waves of 64x64, triple-buffered LDS,
// one barrier per K-tile, counted vmcnt(6).
// ---------------------------------------------------------------------------
#define BAR()  do { __builtin_amdgcn_s_barrier(); __builtin_amdgcn_sched_barrier(0); } while(0)

#define LDA(CA) do {                                                          \
    _Pragma("unroll") for (int mi = 0; mi < 4; ++mi)                          \
    _Pragma("unroll") for (int ks = 0; ks < 2; ++ks)                          \
        af[mi*2+ks] = *(const bf16x8*)((CA) + (wm*64 + mi*16 + lr)*128        \
                                            + (((ks*4 + lk) ^ lm)<<4));      \
} while(0)

#define LDB(CB) do {                                                          \
    _Pragma("unroll") for (int j2 = 0; j2 < 4; ++j2)                          \
    _Pragma("unroll") for (int ks = 0; ks < 2; ++ks)                          \
        bfr[j2*2+ks] = *(const bf16x8*)((CB) + (wn*64 + j2*16 + lr)*128       \
                                             + (((ks*4 + lk) ^ lm)<<4));     \
} while(0)

#define MMQ_ALL() do {                                                        \
    __builtin_amdgcn_s_setprio(1);                                            \
    _Pragma("unroll") for (int ks = 0; ks < 2; ++ks)                          \
    _Pragma("unroll") for (int mi = 0; mi < 4; ++mi)                          \
    _Pragma("unroll") for (int j2 = 0; j2 < 4; ++j2)                          \
        acc[mi][j2] = __builtin_amdgcn_mfma_f32_16x16x32_bf16(                \
            af[mi*2+ks], bfr[j2*2+ks], acc[mi][j2], 0, 0, 0);                 \
    __builtin_amdgcn_s_setprio(0);                                            \
} while(0)

#define STAGE_A2(SA, kt) do {                                                 \
    const char* _g = AgT + (size_t)(kt)*128;                                  \
    char* _l = (SA) + wave*1024;                                              \
    async16(_g, _l); async16(_g + 64*(size_t)AstB, _l + 8192);                \
} while(0)

#define STAGE_B4(SB, kt) do {                                                 \
    const char* _g = BgT + (size_t)(kt)*128;                                  \
    char* _l = (SB) + wave*1024;                                              \
    async16(_g, _l);                                                          \
    async16(_g +  64*(size_t)AstB, _l + 8192);                                \
    async16(_g + 128*(size_t)AstB, _l + 16384);                               \
    async16(_g + 192*(size_t)AstB, _l + 24576);                               \
} while(0)

__device__ __forceinline__ void gemm_tile(
    const bf16* __restrict__ args, const bf16* __restrict__ dpad,
    const float* __restrict__ root_filler, const float* __restrict__ root_role,
    float* __restrict__ out, char* lds, int job, int mt, int nt)
{
    const bf16* Ab = (job==0) ? args : (job==1) ? args+4194304 : args+8388608;
    const bf16* Bb = (job==0) ? dpad : (job==1) ? dpad+1048576 : dpad+2097152;
    const int AstB = (job < 2) ? 2048 : 4096;      // row stride BYTES (A and B)
    const int nkt  = (job < 2) ? 16 : 32;          // K/64

    const int tid  = threadIdx.x;
    const int wave = tid >> 6, lane = tid & 63;
    const int wm   = wave >> 2, wn = wave & 3;     // 2M x 4N, wave = 64x64
    const int lr   = lane & 15, lk = lane >> 4, lm = lane & 7;

    const char* AgT = (const char*)Ab + (size_t)(mt*128 + (tid>>3))*AstB + (tid&7)*16;
    const char* BgT = (const char*)Bb + (size_t)(nt*256 + (tid>>3))*AstB + (tid&7)*16;

    f32x4 acc[4][4] = {};
    bf16x8 af[8], bfr[8];

    // prologue: kt0 -> buf0, kt1 -> buf1 (6 units each); wait kt0 landed
    // (vmcnt also drains any still-outstanding epilogue stores of a prior tile)
    STAGE_A2(lds,         0); STAGE_B4(lds + 49152, 0);
    STAGE_A2(lds + 16384, 1); STAGE_B4(lds + 81920, 1);
    asm volatile("s_waitcnt vmcnt(6)" ::: "memory");
    BAR();

    int cb = 0;
    for (int kt = 0; kt < nkt; ++kt) {
        char* cA = lds + cb*16384;
        char* cB = lds + 49152 + cb*32768;
        int sb = cb + 2; if (sb >= 3) sb -= 3;
        char* sA = lds + sb*16384;
        char* sB = lds + 49152 + sb*32768;
        const bool st = (kt + 2 < nkt);
        LDA(cA); LDB(cB);
        if (st) { STAGE_A2(sA, kt+2); STAGE_B4(sB, kt+2); }
        MMQ_ALL();
        if (st)                { asm volatile("s_waitcnt vmcnt(6)" ::: "memory"); }
        else if (kt == nkt-2)  { asm volatile("s_waitcnt vmcnt(0)" ::: "memory"); }
        BAR();
        cb = cb + 1; if (cb == 3) cb = 0;
    }

    float* outp = out + (size_t)job * BFR;
#pragma unroll
    for (int mi = 0; mi < 4; ++mi) {
        const int gm0 = mt*128 + wm*64 + mi*16 + lk*4;
#pragma unroll
        for (int j = 0; j < 4; ++j) {
            const int gn = nt*256 + wn*64 + j*16 + lr;
            if (gn < Rdim) {
                const float rr = (job == 2) ? root_role[gn] : 0.f;
#pragma unroll
                for (int q = 0; q < 4; ++q) {
                    const int gm = gm0 + q;
                    float v = acc[mi][j][q];
                    if (job == 2) v += root_filler[gm] * rr;
                    outp[(size_t)gm*Rdim + gn] = v;
                }
            }
        }
    }
}

// ---------------------------------------------------------------------------
// Fused producer/consumer kernel. 256 blocks x 512 thr, 144 KiB LDS
// (1 block/CU; grid == CU count).
// Blocks 0..127 produce: dpad (flag[0]) then 16 args batches (flags[1+k],
// batch k = rows [256k,256k+256) = panels 2k,2k+1), then join consuming.
// Blocks 128..255 consume immediately: atomic ticket queue ordered by panel
// group (24 tiles/group: 8 cons + 8 car + 8 cdr), acquire-spin on group flag.
// Deadlock-free: producers depend on nothing and retire; dep graph acyclic.
// ---------------------------------------------------------------------------
__global__ __launch_bounds__(512, 1) void k_fused(
    const float* __restrict__ x,
    const float* __restrict__ w0, const float* __restrict__ w1,
    const float* __restrict__ w2, const float* __restrict__ w3,
    const float* __restrict__ Dl, const float* __restrict__ Dr,
    const float* __restrict__ El, const float* __restrict__ Er,
    const float* __restrict__ root_filler, const float* __restrict__ root_role,
    bf16* __restrict__ args, bf16* __restrict__ dpad,
    float* __restrict__ out, uint* __restrict__ flags)
{
    __shared__ char lds[147456];
    const int bid = blockIdx.x;
    const int tid = threadIdx.x;

    if (bid < 128) {
        // ---------------- producer ----------------
#pragma unroll
        for (int i = 0; i < 8; ++i)
            prep_dpad_chunk(bid*4096 + i*512 + tid, Dl, Dr, El, Er, dpad);
        __threadfence();               // agent release: L2 writeback
        __syncthreads();
        if (tid == 0)
            __hip_atomic_fetch_add(&flags[0], 1u, __ATOMIC_RELEASE,
                                   __HIP_MEMORY_SCOPE_AGENT);
        const int h = tid >> 8, t = tid & 255;
        for (int k = 0; k < 16; ++k) {
            prep_args_row(k*256 + bid*2 + h, t, x, w0, w1, w2, w3, args);
            __threadfence();
            __syncthreads();
            if (tid == 0)
                __hip_atomic_fetch_add(&flags[1+k], 1u, __ATOMIC_RELEASE,
                                       __HIP_MEMORY_SCOPE_AGENT);
        }
        if (bid == 0 && tid < 256) prep_stats(tid, w0, w1, w2, w3, out);
    }

    // ---------------- consumer (everyone, producers join after prep) -------
    // gate: dpad complete (B operand needed by every tile from kt0)
    if (tid == 0) {
        while (__hip_atomic_load(&flags[0], __ATOMIC_ACQUIRE,
                                 __HIP_MEMORY_SCOPE_AGENT) < 128u)
            __builtin_amdgcn_s_sleep(8);
    }
    __syncthreads();

    for (;;) {
        if (tid == 0) {
            uint tk = __hip_atomic_fetch_add(&flags[17], 1u, __ATOMIC_RELAXED,
                                             __HIP_MEMORY_SCOPE_AGENT);
            *(volatile uint*)lds = tk;
        }
        __syncthreads();
        const uint tk = *(volatile uint*)lds;
        __syncthreads();
        if (tk >= 384u) break;

        const int g  = tk / 24;            // panel group = batch index
        const int r  = tk % 24;            // cons first (2-unit tiles longest)
        const int job = (r < 8) ? 2 : (r < 16) ? 0 : 1;
        const int ci  = g*8 + (r & 7);     // tile index within job
        const int mt  = ci >> 2, nt = ci & 3;

        if (tid == 0) {
            while (__hip_atomic_load(&flags[1+g], __ATOMIC_ACQUIRE,
                                     __HIP_MEMORY_SCOPE_AGENT) < 128u)
                __builtin_amdgcn_s_sleep(8);
        }
        __syncthreads();

        gemm_tile(args, dpad, root_filler, root_role, out, lds, job, mt, nt);
        __syncthreads();   // all LDS reads of this tile done before next ticket
    }
}

// ---------------------------------------------------------------------------
extern "C" void kernel_launch(void* const* d_in, const int* in_sizes, int n_in,
                              void* d_out, int out_size, void* d_ws, size_t ws_size,
                              hipStream_t stream)
{
    const float* x           = (const float*)d_in[0];
    const float* car_w       = (const float*)d_in[1];
    const float* cdr_w       = (const float*)d_in[2];
    const float* cons1_w     = (const float*)d_in[3];
    const float* cons2_w     = (const float*)d_in[4];
    const float* root_filler = (const float*)d_in[5];
    const float* Dl          = (const float*)d_in[6];
    const float* Dr          = (const float*)d_in[7];
    const float* El          = (const float*)d_in[8];
    const float* Er          = (const float*)d_in[9];
    const float* root_role   = (const float*)d_in[10];
    float* out = (float*)d_out;

    bf16* args  = (bf16*)d_ws;                            // 33.5 MB
    bf16* dpad  = args + 16777216;                        //  8.4 MB
    uint* flags = (uint*)((char*)d_ws + 41943040);        // 18 uints

    hipMemsetAsync(flags, 0, 18 * sizeof(uint), stream);  // reset every call
    k_fused<<<dim3(256), dim3(512), 0, stream>>>(
        x, car_w, cdr_w, cons1_w, cons2_w, Dl, Dr, El, Er,
        root_filler, root_role, args, dpad, out, flags);
}

// Round 9
// 113.427 us; speedup vs baseline: 9.8732x; 9.8732x over previous
//
#include <hip/hip_runtime.h>
#include <hip/hip_bf16.h>
#include <stdint.h>

#define Rdim 1023
#define BFR  4190208           // 64*64*1023

typedef __bf16 bf16;
typedef __bf16 bf16x8 __attribute__((ext_vector_type(8)));
typedef __bf16 bf16x4 __attribute__((ext_vector_type(4)));
typedef float  f32x4  __attribute__((ext_vector_type(4)));
typedef float  f32x4u __attribute__((ext_vector_type(4), aligned(4)));

__device__ __forceinline__ void async16(const void* g, void* l) {
    __builtin_amdgcn_global_load_lds(
        (const __attribute__((address_space(1))) void*)g,
        (__attribute__((address_space(3))) void*)l, 16, 0, 0);
}

// ---------------------------------------------------------------------------
// Fused prep kernel (r7 verbatim — proven, near HBM floor).
// Swizzle: 16B chunk c of row m stored at chunk (c ^ (m&7)) within its
// 128B (8-chunk) window -> GEMM staging is a LINEAR copy, ds_read XORs.
// ---------------------------------------------------------------------------
__global__ __launch_bounds__(256) void k_prep(
    const float* __restrict__ x,
    const float* __restrict__ w0, const float* __restrict__ w1,
    const float* __restrict__ w2, const float* __restrict__ w3,
    const float* __restrict__ Dl, const float* __restrict__ Dr,
    const float* __restrict__ El, const float* __restrict__ Er,
    bf16* __restrict__ args, bf16* __restrict__ dpad,
    float* __restrict__ out)
{
    const int blk = blockIdx.x;
    const int t   = threadIdx.x;

    if (blk < 4096) {
        const int b = blk >> 6;
        float wr0[16], wr1[16], wr2[16], wr3[16];
#pragma unroll
        for (int l = 0; l < 16; ++l) {
            wr0[l] = w0[b*16 + l]; wr1[l] = w1[b*16 + l];
            wr2[l] = w2[b*16 + l]; wr3[l] = w3[b*16 + l];
        }
        const float* xb = x + ((size_t)(b*16)*64 + (blk & 63)) * (size_t)Rdim;
        float a0[4] = {}, a1[4] = {}, a2[4] = {}, a3[4] = {};
        if (t < 255) {
#pragma unroll
            for (int l = 0; l < 16; ++l) {
                f32x4u v = *(const f32x4u*)(xb + (size_t)l*(64*(size_t)Rdim) + t*4);
#pragma unroll
                for (int j = 0; j < 4; ++j) {
                    a0[j] += wr0[l]*v[j]; a1[j] += wr1[l]*v[j];
                    a2[j] += wr2[l]*v[j]; a3[j] += wr3[l]*v[j];
                }
            }
        } else {
#pragma unroll
            for (int l = 0; l < 16; ++l) {
                const float* p = xb + (size_t)l*(64*(size_t)Rdim) + 1020;
#pragma unroll
                for (int j = 0; j < 3; ++j) {
                    float v = p[j];
                    a0[j] += wr0[l]*v; a1[j] += wr1[l]*v;
                    a2[j] += wr2[l]*v; a3[j] += wr3[l]*v;
                }
            }
        }
        const int c   = t >> 1;
        const int S   = blk & 7;
        const int off = ((c ^ S) << 3) + ((t & 1) << 2);
        bf16x4 s0, s1, s2, s3;
#pragma unroll
        for (int j = 0; j < 4; ++j) {
            s0[j] = (bf16)a0[j]; s1[j] = (bf16)a1[j];
            s2[j] = (bf16)a2[j]; s3[j] = (bf16)a3[j];
        }
        *(bf16x4*)(args +            (size_t)blk*1024 + off) = s0;
        *(bf16x4*)(args + 4194304 +  (size_t)blk*1024 + off) = s1;
        bf16* c12 = args + 8388608 + (size_t)blk*2048;
        *(bf16x4*)(c12 + off)        = s2;
        *(bf16x4*)(c12 + 1024 + off) = s3;
    } else if (blk < 6144) {
        const int id = (blk - 4096)*256 + t;
        const float* src; int n, c, K; size_t base;
        if (id < 262144) {
            const int m2  = id >> 17;
            src = m2 ? Dr : Dl;
            const int rem = id & 131071;
            n = rem >> 7; c = rem & 127; K = 1024;
            base = m2 ? 1048576u : 0u;
        } else {
            const int rem = id - 262144;
            n = rem >> 8; c = rem & 255; K = 2048;
            base = 2097152u;
            src = (c < 128) ? El : Er;
        }
        const int cl = c & 127;
        float v[8] = {};
        if (n < Rdim) {
            const float* sp = src + (size_t)n*Rdim + cl*8;
            if (cl < 127) {
                f32x4u u0 = *(const f32x4u*)sp;
                f32x4u u1 = *(const f32x4u*)(sp + 4);
#pragma unroll
                for (int j = 0; j < 4; ++j) { v[j] = u0[j]; v[4+j] = u1[j]; }
            } else {
                f32x4u u0 = *(const f32x4u*)sp;
#pragma unroll
                for (int j = 0; j < 4; ++j) v[j] = u0[j];
                v[4] = sp[4]; v[5] = sp[5]; v[6] = sp[6];
            }
        }
        const int swc = c ^ (n & 7);
        bf16x8 s;
#pragma unroll
        for (int j = 0; j < 8; ++j) s[j] = (bf16)v[j];
        *(bf16x8*)(dpad + base + (size_t)n*K + swc*8) = s;
    } else {
        const int k = t >> 6, b2 = t & 63;
        const float* w = (k==0) ? w0 : (k==1) ? w1 : (k==2) ? w2 : w3;
        float s = 0.f, mx = -1e30f;
#pragma unroll
        for (int l = 0; l < 16; ++l) {
            float p = w[b2*16 + l];
            s += p * logf(p + 1e-12f);
            mx = fmaxf(mx, p);
        }
        out[3*(size_t)BFR +       k*64 + b2] = -s / logf(16.f);
        out[3*(size_t)BFR + 256 + k*64 + b2] = mx;
    }
}

// ---------------------------------------------------------------------------
// 64x128 MFMA GEMM, 256 thr (4 waves of 32x64), triple-buffered 72 KiB LDS
// -> 2 blocks/CU (cross-block hiding of barrier+vmcnt stalls; the r8 lesson
// killed flag-based overlap, this is the safe occupancy-based version).
// Same 1-phase loop, XOR-chunk swizzle (BK=64 keeps 128B windows -> prep
// unchanged), counted vmcnt(6), cons-first XCD packing.
// LDS: A 3 x 8 KB @0, B 3 x 16 KB @24576. grid = 1536 blocks.
// ---------------------------------------------------------------------------
#define BAR()  do { __builtin_amdgcn_s_barrier(); __builtin_amdgcn_sched_barrier(0); } while(0)

// A frags: row = wm*32 + mi*16 + lr (mi 0..1), chunk = (ks*4 + lk) ^ (lr&7)
#define LDA(CA) do {                                                          \
    _Pragma("unroll") for (int mi = 0; mi < 2; ++mi)                          \
    _Pragma("unroll") for (int ks = 0; ks < 2; ++ks)                          \
        af[mi*2+ks] = *(const bf16x8*)((CA) + (wm*32 + mi*16 + lr)*128        \
                                            + (((ks*4 + lk) ^ lm)<<4));      \
} while(0)

// B frags: row = wn*64 + j2*16 + lr (j2 0..3)
#define LDB(CB) do {                                                          \
    _Pragma("unroll") for (int j2 = 0; j2 < 4; ++j2)                          \
    _Pragma("unroll") for (int ks = 0; ks < 2; ++ks)                          \
        bfr[j2*2+ks] = *(const bf16x8*)((CB) + (wn*64 + j2*16 + lr)*128       \
                                             + (((ks*4 + lk) ^ lm)<<4));     \
} while(0)

#define MMQ_ALL() do {                                                        \
    __builtin_amdgcn_s_setprio(1);                                            \
    _Pragma("unroll") for (int ks = 0; ks < 2; ++ks)                          \
    _Pragma("unroll") for (int mi = 0; mi < 2; ++mi)                          \
    _Pragma("unroll") for (int j2 = 0; j2 < 4; ++j2)                          \
        acc[mi][j2] = __builtin_amdgcn_mfma_f32_16x16x32_bf16(                \
            af[mi*2+ks], bfr[j2*2+ks], acc[mi][j2], 0, 0, 0);                 \
    __builtin_amdgcn_s_setprio(0);                                            \
} while(0)

// 256 threads cover 32 rows x 128 B per issue; A (64 rows) = 2 issues,
// B (128 rows) = 4 issues; LDS per issue = 4 KB, wave-uniform base + lane*16.
#define STAGE_A2(SA, kt) do {                                                 \
    const char* _g = AgT + (size_t)(kt)*128;                                  \
    char* _l = (SA) + wave*1024;                                              \
    async16(_g, _l); async16(_g + 32*(size_t)AstB, _l + 4096);                \
} while(0)

#define STAGE_B4(SB, kt) do {                                                 \
    const char* _g = BgT + (size_t)(kt)*128;                                  \
    char* _l = (SB) + wave*1024;                                              \
    async16(_g, _l);                                                          \
    async16(_g + 32*(size_t)AstB, _l + 4096);                                 \
    async16(_g + 64*(size_t)AstB, _l + 8192);                                 \
    async16(_g + 96*(size_t)AstB, _l + 12288);                                \
} while(0)

__global__ __launch_bounds__(256, 2) void k_gemm2b(
    const bf16* __restrict__ args, const bf16* __restrict__ dpad,
    const float* __restrict__ root_filler, const float* __restrict__ root_role,
    float* __restrict__ out)
{
    __shared__ char lds[73728];       // 72 KiB -> 2 blocks/CU

    const int bid = blockIdx.x;       // 0..1535
    const int xcd = bid & 7, idx = bid >> 3;       // idx 0..191
    int job, tile;
    if (idx < 64)       { job = 2; tile = xcd*64 + idx;       } // cons FIRST
    else if (idx < 128) { job = 0; tile = xcd*64 + idx - 64;  } // car
    else                { job = 1; tile = xcd*64 + idx - 128; } // cdr
    const int mt = tile >> 3;         // 0..63
    const int nt = tile & 7;          // 0..7

    const bf16* Ab = (job==0) ? args : (job==1) ? args+4194304 : args+8388608;
    const bf16* Bb = (job==0) ? dpad : (job==1) ? dpad+1048576 : dpad+2097152;
    const int AstB = (job < 2) ? 2048 : 4096;      // row stride BYTES (A and B)
    const int nkt  = (job < 2) ? 16 : 32;          // K/64

    const int tid  = threadIdx.x;
    const int wave = tid >> 6, lane = tid & 63;
    const int wm   = wave >> 1, wn = wave & 1;     // 2M x 2N, wave = 32x64
    const int lr   = lane & 15, lk = lane >> 4, lm = lane & 7;

    const char* AgT = (const char*)Ab + (size_t)(mt*64  + (tid>>3))*AstB + (tid&7)*16;
    const char* BgT = (const char*)Bb + (size_t)(nt*128 + (tid>>3))*AstB + (tid&7)*16;

    f32x4 acc[2][4] = {};
    bf16x8 af[4], bfr[8];

    // prologue: kt0 -> buf0, kt1 -> buf1 (6 units each); wait kt0 landed
    STAGE_A2(lds,        0); STAGE_B4(lds + 24576, 0);
    STAGE_A2(lds + 8192, 1); STAGE_B4(lds + 40960, 1);
    asm volatile("s_waitcnt vmcnt(6)" ::: "memory");
    BAR();

    int cb = 0;
    for (int kt = 0; kt < nkt; ++kt) {
        char* cA = lds + cb*8192;
        char* cB = lds + 24576 + cb*16384;
        int sb = cb + 2; if (sb >= 3) sb -= 3;
        char* sA = lds + sb*8192;
        char* sB = lds + 24576 + sb*16384;
        const bool st = (kt + 2 < nkt);
        LDA(cA); LDB(cB);
        if (st) { STAGE_A2(sA, kt+2); STAGE_B4(sB, kt+2); }
        MMQ_ALL();
        if (st)                { asm volatile("s_waitcnt vmcnt(6)" ::: "memory"); }
        else if (kt == nkt-2)  { asm volatile("s_waitcnt vmcnt(0)" ::: "memory"); }
        BAR();
        cb = cb + 1; if (cb == 3) cb = 0;
    }

    // epilogue: 16x16 C/D: col = lane&15, row = (lane>>4)*4 + q
    float* outp = out + (size_t)job * BFR;
#pragma unroll
    for (int mi = 0; mi < 2; ++mi) {
        const int gm0 = mt*64 + wm*32 + mi*16 + lk*4;
#pragma unroll
        for (int j = 0; j < 4; ++j) {
            const int gn = nt*128 + wn*64 + j*16 + lr;
            if (gn < Rdim) {
                const float rr = (job == 2) ? root_role[gn] : 0.f;
#pragma unroll
                for (int q = 0; q < 4; ++q) {
                    const int gm = gm0 + q;
                    float v = acc[mi][j][q];
                    if (job == 2) v += root_filler[gm] * rr;
                    outp[(size_t)gm*Rdim + gn] = v;
                }
            }
        }
    }
}

// ---------------------------------------------------------------------------
extern "C" void kernel_launch(void* const* d_in, const int* in_sizes, int n_in,
                              void* d_out, int out_size, void* d_ws, size_t ws_size,
                              hipStream_t stream)
{
    const float* x           = (const float*)d_in[0];
    const float* car_w       = (const float*)d_in[1];
    const float* cdr_w       = (const float*)d_in[2];
    const float* cons1_w     = (const float*)d_in[3];
    const float* cons2_w     = (const float*)d_in[4];
    const float* root_filler = (const float*)d_in[5];
    const float* Dl          = (const float*)d_in[6];
    const float* Dr          = (const float*)d_in[7];
    const float* El          = (const float*)d_in[8];
    const float* Er          = (const float*)d_in[9];
    const float* root_role   = (const float*)d_in[10];
    float* out = (float*)d_out;

    bf16* args = (bf16*)d_ws;                 // 33.5 MB
    bf16* dpad = args + 16777216;             //  8.4 MB

    k_prep  <<<dim3(6145), dim3(256), 0, stream>>>(
        x, car_w, cdr_w, cons1_w, cons2_w, Dl, Dr, El, Er, args, dpad, out);
    k_gemm2b<<<dim3(1536), dim3(256), 0, stream>>>(
        args, dpad, root_filler, root_role, out);
}

// Round 10
// 107.136 us; speedup vs baseline: 10.4529x; 1.0587x over previous
//
#include <hip/hip_runtime.h>
#include <hip/hip_bf16.h>
#include <stdint.h>

#define Rdim 1023
#define BFR  4190208           // 64*64*1023

typedef __bf16 bf16;
typedef __bf16 bf16x8 __attribute__((ext_vector_type(8)));
typedef __bf16 bf16x4 __attribute__((ext_vector_type(4)));
typedef float  f32x4  __attribute__((ext_vector_type(4)));
typedef float  f32x4u __attribute__((ext_vector_type(4), aligned(4)));

__device__ __forceinline__ void async16(const void* g, void* l) {
    __builtin_amdgcn_global_load_lds(
        (const __attribute__((address_space(1))) void*)g,
        (__attribute__((address_space(3))) void*)l, 16, 0, 0);
}

#define BAR()  do { __builtin_amdgcn_s_barrier(); __builtin_amdgcn_sched_barrier(0); } while(0)

// ---------------------------------------------------------------------------
// Fused prep kernel. NEW 2-bit swizzle for BK=32: 16B chunk c of row m stored
// at (c&~3) | ((c&3) ^ ((m>>1)&3)) — permutes within each 64-B window, so a
// BK=32 (64-B) K-tile is still a LINEAR copy for global_load_lds staging.
// ---------------------------------------------------------------------------
__global__ __launch_bounds__(256) void k_prep(
    const float* __restrict__ x,
    const float* __restrict__ w0, const float* __restrict__ w1,
    const float* __restrict__ w2, const float* __restrict__ w3,
    const float* __restrict__ Dl, const float* __restrict__ Dr,
    const float* __restrict__ El, const float* __restrict__ Er,
    bf16* __restrict__ args, bf16* __restrict__ dpad,
    float* __restrict__ out)
{
    const int blk = blockIdx.x;
    const int t   = threadIdx.x;

    if (blk < 4096) {
        const int b = blk >> 6;
        float wr0[16], wr1[16], wr2[16], wr3[16];
#pragma unroll
        for (int l = 0; l < 16; ++l) {
            wr0[l] = w0[b*16 + l]; wr1[l] = w1[b*16 + l];
            wr2[l] = w2[b*16 + l]; wr3[l] = w3[b*16 + l];
        }
        const float* xb = x + ((size_t)(b*16)*64 + (blk & 63)) * (size_t)Rdim;
        float a0[4] = {}, a1[4] = {}, a2[4] = {}, a3[4] = {};
        if (t < 255) {
#pragma unroll
            for (int l = 0; l < 16; ++l) {
                f32x4u v = *(const f32x4u*)(xb + (size_t)l*(64*(size_t)Rdim) + t*4);
#pragma unroll
                for (int j = 0; j < 4; ++j) {
                    a0[j] += wr0[l]*v[j]; a1[j] += wr1[l]*v[j];
                    a2[j] += wr2[l]*v[j]; a3[j] += wr3[l]*v[j];
                }
            }
        } else {
#pragma unroll
            for (int l = 0; l < 16; ++l) {
                const float* p = xb + (size_t)l*(64*(size_t)Rdim) + 1020;
#pragma unroll
                for (int j = 0; j < 3; ++j) {
                    float v = p[j];
                    a0[j] += wr0[l]*v; a1[j] += wr1[l]*v;
                    a2[j] += wr2[l]*v; a3[j] += wr3[l]*v;
                }
            }
        }
        const int c   = t >> 1;                       // 16B chunk = r/8
        const int S2  = (blk >> 1) & 3;               // 2-bit row swizzle
        const int cw  = (c & ~3) | ((c & 3) ^ S2);
        const int off = (cw << 3) + ((t & 1) << 2);
        bf16x4 s0, s1, s2, s3;
#pragma unroll
        for (int j = 0; j < 4; ++j) {
            s0[j] = (bf16)a0[j]; s1[j] = (bf16)a1[j];
            s2[j] = (bf16)a2[j]; s3[j] = (bf16)a3[j];
        }
        *(bf16x4*)(args +            (size_t)blk*1024 + off) = s0;
        *(bf16x4*)(args + 4194304 +  (size_t)blk*1024 + off) = s1;
        bf16* c12 = args + 8388608 + (size_t)blk*2048;
        *(bf16x4*)(c12 + off)        = s2;
        *(bf16x4*)(c12 + 1024 + off) = s3;
    } else if (blk < 6144) {
        const int id = (blk - 4096)*256 + t;
        const float* src; int n, c, K; size_t base;
        if (id < 262144) {
            const int m2  = id >> 17;
            src = m2 ? Dr : Dl;
            const int rem = id & 131071;
            n = rem >> 7; c = rem & 127; K = 1024;
            base = m2 ? 1048576u : 0u;
        } else {
            const int rem = id - 262144;
            n = rem >> 8; c = rem & 255; K = 2048;
            base = 2097152u;
            src = (c < 128) ? El : Er;
        }
        const int cl = c & 127;
        float v[8] = {};
        if (n < Rdim) {
            const float* sp = src + (size_t)n*Rdim + cl*8;
            if (cl < 127) {
                f32x4u u0 = *(const f32x4u*)sp;
                f32x4u u1 = *(const f32x4u*)(sp + 4);
#pragma unroll
                for (int j = 0; j < 4; ++j) { v[j] = u0[j]; v[4+j] = u1[j]; }
            } else {
                f32x4u u0 = *(const f32x4u*)sp;
#pragma unroll
                for (int j = 0; j < 4; ++j) v[j] = u0[j];
                v[4] = sp[4]; v[5] = sp[5]; v[6] = sp[6];
            }
        }
        const int swc = (c & ~3) | ((c & 3) ^ ((n >> 1) & 3));
        bf16x8 s;
#pragma unroll
        for (int j = 0; j < 8; ++j) s[j] = (bf16)v[j];
        *(bf16x8*)(dpad + base + (size_t)n*K + swc*8) = s;
    } else {
        const int k = t >> 6, b2 = t & 63;
        const float* w = (k==0) ? w0 : (k==1) ? w1 : (k==2) ? w2 : w3;
        float s = 0.f, mx = -1e30f;
#pragma unroll
        for (int l = 0; l < 16; ++l) {
            float p = w[b2*16 + l];
            s += p * logf(p + 1e-12f);
            mx = fmaxf(mx, p);
        }
        out[3*(size_t)BFR +       k*64 + b2] = -s / logf(16.f);
        out[3*(size_t)BFR + 256 + k*64 + b2] = mx;
    }
}

// ---------------------------------------------------------------------------
// High-intensity GEMM tile, BK=32, triple-buffered, r7-proven 1-barrier loop.
// car/cdr: BM=256 (stages 32 KB per 2048 compute-cyc -> 26 B/cyc, under the
// ~56 B/cyc per-CU L2 ceiling; r7's 128-tile needed ~100). cons: BM=128,
// K=2048. 256 blocks total, each exactly ONE work unit (16.6 us MFMA floor).
// 8 waves 2M x 4N; per kt all MI*4 MFMAs are independent chains (no ks dim).
// LDS: A 3 x BM*64 @0, B 3 x 16 KB @49152 (96 KB max).
// ---------------------------------------------------------------------------
template<int BM, int NKT, int VM, bool CONS>
__device__ __forceinline__ void gemm_t(
    const bf16* __restrict__ Ab, const bf16* __restrict__ Bb,
    const float* __restrict__ rf, const float* __restrict__ rr,
    float* __restrict__ outp, char* lds, int mt, int nt)
{
    constexpr int AstB = CONS ? 4096 : 2048;   // row stride in bytes (A and B)
    constexpr int MI   = BM / 32;              // A frags per wave (8 or 4)
    constexpr int ABUF = BM * 64;              // bytes per A buffer

    const int tid  = threadIdx.x;
    const int wave = tid >> 6, lane = tid & 63;
    const int wm   = wave >> 2, wn = wave & 3; // 2M x 4N
    const int lr   = lane & 15, lk = lane >> 4;
    const int cc16 = (lk ^ ((lr >> 1) & 3)) << 4;   // swizzled chunk byte-off

    // staging map: thread t covers row tid>>2 (+i*128), chunk tid&3 (16 B)
    const char* AgT = (const char*)Ab + (size_t)(mt*BM  + (tid>>2))*AstB + (tid&3)*16;
    const char* BgT = (const char*)Bb + (size_t)(nt*256 + (tid>>2))*AstB + (tid&3)*16;

    f32x4 acc[MI][4] = {};
    bf16x8 af[MI], bfr[4];

#define STG(bufidx, kt) do {                                                  \
    char* _a = lds + (bufidx)*ABUF + wave*1024;                               \
    char* _b = lds + 49152 + (bufidx)*16384 + wave*1024;                      \
    const size_t _ko = (size_t)(kt)*64;                                       \
    _Pragma("unroll") for (int i = 0; i < BM/128; ++i)                        \
        async16(AgT + (size_t)(i*128)*AstB + _ko, _a + i*8192);               \
    _Pragma("unroll") for (int i = 0; i < 2; ++i)                             \
        async16(BgT + (size_t)(i*128)*AstB + _ko, _b + i*8192);               \
} while(0)

    // prologue: kt0 -> buf0, kt1 -> buf1; wait kt0 landed (kt1's VM remain)
    STG(0, 0); STG(1, 1);
    asm volatile("s_waitcnt vmcnt(%0)" :: "n"(VM) : "memory");
    BAR();

    int cb = 0;
    for (int kt = 0; kt < NKT; ++kt) {
        char* cA = lds + cb*ABUF;
        char* cB = lds + 49152 + cb*16384;
        int sb = cb + 2; if (sb >= 3) sb -= 3;
        const bool st = (kt + 2 < NKT);
#pragma unroll
        for (int mi = 0; mi < MI; ++mi)
            af[mi] = *(const bf16x8*)(cA + (wm*(BM/2) + mi*16 + lr)*64 + cc16);
#pragma unroll
        for (int j = 0; j < 4; ++j)
            bfr[j] = *(const bf16x8*)(cB + (wn*64 + j*16 + lr)*64 + cc16);
        if (st) STG(sb, kt+2);
        __builtin_amdgcn_s_setprio(1);
#pragma unroll
        for (int mi = 0; mi < MI; ++mi)
#pragma unroll
        for (int j = 0; j < 4; ++j)
            acc[mi][j] = __builtin_amdgcn_mfma_f32_16x16x32_bf16(
                af[mi], bfr[j], acc[mi][j], 0, 0, 0);
        __builtin_amdgcn_s_setprio(0);
        if (st)                { asm volatile("s_waitcnt vmcnt(%0)" :: "n"(VM) : "memory"); }
        else if (kt == NKT-2)  { asm volatile("s_waitcnt vmcnt(0)" ::: "memory"); }
        BAR();
        cb = cb + 1; if (cb == 3) cb = 0;
    }
#undef STG

    // epilogue: 16x16 C/D: col = lane&15, row = (lane>>4)*4 + q
#pragma unroll
    for (int mi = 0; mi < MI; ++mi) {
        const int gm0 = mt*BM + wm*(BM/2) + mi*16 + lk*4;
#pragma unroll
        for (int j = 0; j < 4; ++j) {
            const int gn = nt*256 + wn*64 + j*16 + lr;
            if (gn < Rdim) {
                const float rv = CONS ? rr[gn] : 0.f;
#pragma unroll
                for (int q = 0; q < 4; ++q) {
                    float v = acc[mi][j][q];
                    if (CONS) v += rf[gm0 + q] * rv;
                    outp[(size_t)(gm0 + q)*Rdim + gn] = v;
                }
            }
        }
    }
}

// 256 blocks: per XCD 16 cons (128x256, K=2048) + 8 car + 8 cdr (256x256,
// K=1024) — every block exactly one work unit, single dispatch round.
__global__ __launch_bounds__(512, 1) void k_gemm(
    const bf16* __restrict__ args, const bf16* __restrict__ dpad,
    const float* __restrict__ root_filler, const float* __restrict__ root_role,
    float* __restrict__ out)
{
    __shared__ char lds[98304];       // 96 KiB
    const int bid = blockIdx.x;
    const int xcd = bid & 7, idx = bid >> 3;   // idx 0..31

    if (idx < 16) {
        const int tile = xcd*16 + idx;         // 0..127: mt 0..31, nt 0..3
        gemm_t<128, 64, 3, true >(args + 8388608, dpad + 2097152,
            root_filler, root_role, out + 2*(size_t)BFR, lds, tile >> 2, tile & 3);
    } else if (idx < 24) {
        const int tile = xcd*8 + idx - 16;     // 0..63: mt 0..15, nt 0..3
        gemm_t<256, 32, 4, false>(args, dpad,
            root_filler, root_role, out, lds, tile >> 2, tile & 3);
    } else {
        const int tile = xcd*8 + idx - 24;
        gemm_t<256, 32, 4, false>(args + 4194304, dpad + 1048576,
            root_filler, root_role, out + (size_t)BFR, lds, tile >> 2, tile & 3);
    }
}

// ---------------------------------------------------------------------------
extern "C" void kernel_launch(void* const* d_in, const int* in_sizes, int n_in,
                              void* d_out, int out_size, void* d_ws, size_t ws_size,
                              hipStream_t stream)
{
    const float* x           = (const float*)d_in[0];
    const float* car_w       = (const float*)d_in[1];
    const float* cdr_w       = (const float*)d_in[2];
    const float* cons1_w     = (const float*)d_in[3];
    const float* cons2_w     = (const float*)d_in[4];
    const float* root_filler = (const float*)d_in[5];
    const float* Dl          = (const float*)d_in[6];
    const float* Dr          = (const float*)d_in[7];
    const float* El          = (const float*)d_in[8];
    const float* Er          = (const float*)d_in[9];
    const float* root_role   = (const float*)d_in[10];
    float* out = (float*)d_out;

    bf16* args = (bf16*)d_ws;                 // 33.5 MB
    bf16* dpad = args + 16777216;             //  8.4 MB

    k_prep<<<dim3(6145), dim3(256), 0, stream>>>(
        x, car_w, cdr_w, cons1_w, cons2_w, Dl, Dr, El, Er, args, dpad, out);
    k_gemm<<<dim3(256),  dim3(512), 0, stream>>>(
        args, dpad, root_filler, root_role, out);
}